// Round 12
// baseline (3639.614 us; speedup 1.0000x reference)
//
#include <hip/hip_runtime.h>
#include <hip/hip_bf16.h>
#include <math.h>

// Problem constants
#define B_ 32
#define D_ 192
#define DEPTH_ 4
#define DI_ 384
#define DS_ 16
#define DC_ 4
#define P_ 16
#define IMG_ 224
#define N_ 196
#define L_ 197

// scan chunking
#define NCH 16
#define CHL 13   // 16*13 = 208 >= 197

#define GRID_ 512   // 2 blocks/CU guaranteed by __launch_bounds__(256,2); LDS allows 5

typedef short s16x8 __attribute__((ext_vector_type(8)));
typedef float f32x16 __attribute__((ext_vector_type(16)));

__device__ __forceinline__ float sigmoidf_(float x) { return 1.f / (1.f + expf(-x)); }
__device__ __forceinline__ float bf2f(short s) {
  unsigned int u = ((unsigned int)(unsigned short)s) << 16;
  return __uint_as_float(u);
}
__device__ __forceinline__ short f2bf(float f) {
  __hip_bfloat16 h = __float2bfloat16(f);
  return *(short*)&h;
}

// ---------------- device-scope grid barrier (all GRID_ blocks co-resident) ----------------
__device__ __forceinline__ void gsync(unsigned int* cnt, unsigned int* gen) {
  __syncthreads();
  if (threadIdx.x == 0) {
    __threadfence();  // agent-scope release: drain my writes past L2
    unsigned int g = __hip_atomic_load(gen, __ATOMIC_RELAXED, __HIP_MEMORY_SCOPE_AGENT);
    unsigned int t = __hip_atomic_fetch_add(cnt, 1u, __ATOMIC_ACQ_REL, __HIP_MEMORY_SCOPE_AGENT);
    if (t == GRID_ - 1) {
      __hip_atomic_store(cnt, 0u, __ATOMIC_RELAXED, __HIP_MEMORY_SCOPE_AGENT);
      __hip_atomic_fetch_add(gen, 1u, __ATOMIC_RELEASE, __HIP_MEMORY_SCOPE_AGENT);
    } else {
      while (__hip_atomic_load(gen, __ATOMIC_ACQUIRE, __HIP_MEMORY_SCOPE_AGENT) == g) {
        __builtin_amdgcn_s_sleep(2);
      }
    }
    __threadfence();  // acquire side: invalidate my CU L1 / XCD L2
  }
  __syncthreads();
}

// ---------------- merged im2col + prep (unchanged from r10) ----------------
__global__ __launch_bounds__(256) void k_prep_im2col(
    const float* __restrict__ x, __hip_bfloat16* __restrict__ A,
    const float* __restrict__ patch_w, const float* __restrict__ w_in,
    const float* __restrict__ w_out, const float* __restrict__ w_x,
    const float* __restrict__ cls_tok, const float* __restrict__ pos,
    const float* __restrict__ A_log,
    __hip_bfloat16* __restrict__ pw, __hip_bfloat16* __restrict__ win,
    __hip_bfloat16* __restrict__ wout, __hip_bfloat16* __restrict__ wx,
    float* __restrict__ t, float* __restrict__ Aneg) {
  if (blockIdx.x < 18816) {
    int idx = blockIdx.x * 256 + threadIdx.x;  // 6272*768 exact
    int tok = idx / 768, f = idx - tok * 768;
    int b = tok / 196, p = tok - b * 196;
    int h = p / 14, w = p - h * 14;
    int c = f >> 8, i = (f >> 4) & 15, j = f & 15;
    float v = x[(((size_t)(b * 3 + c) * 224 + h * 16 + i) * 224 + w * 16 + j)];
    A[idx] = __float2bfloat16(v);
    return;
  }
  int idx = (blockIdx.x - 18816) * 256 + threadIdx.x;  // 1,161,216 exact
  if (idx < 147456) { pw[idx] = __float2bfloat16(patch_w[idx]); return; }
  idx -= 147456;
  if (idx < 589824) { win[idx] = __float2bfloat16(w_in[idx]); return; }
  idx -= 589824;
  if (idx < 294912) { wout[idx] = __float2bfloat16(w_out[idx]); return; }
  idx -= 294912;
  if (idx < 98304) {
    int li = idx / 24576;
    int r = (idx / 384) & 63;
    int c = idx % 384;
    wx[idx] = (r < 33) ? __float2bfloat16(w_x[(li * 33 + r) * 384 + c]) : __float2bfloat16(0.f);
    return;
  }
  idx -= 98304;
  if (idx < 6144) {
    int b = idx / 192, d = idx % 192;
    t[(size_t)b * L_ * D_ + d] = cls_tok[d] + pos[d];
    return;
  }
  idx -= 6144;
  Aneg[idx] = -expf(A_log[idx]);  // 24576
}

struct MP {
  const short* Abuf; const short* pw; const float* patch_b; const float* pos;
  float* t;
  const float* ln_g; const float* ln_b;
  const short* win;
  __hip_bfloat16* xln;
  __hip_bfloat16* xz;
  const float* conv_w; const float* conv_b;
  __hip_bfloat16* xa; __hip_bfloat16* sz;
  const short* wx;
  float* bcd;
  const float* Aneg; const float* w_dt; const float* b_dt; const float* D_ssm;
  float* Pst; float* Hst;
  __hip_bfloat16* y;
  const short* wout;
  const float* fn_g; const float* fn_b; const float* cls_w; const float* cls_b;
  const float* rw1; const float* rb1; const float* rw2; const float* rb2;
  float* out;
  unsigned int* bar;  // [0]=count, [1]=gen (zeroed by memset each call)
};

// r7/r10-verified tile compute: KC=96, STR=104, 26.6 KB LDS
template <int KTOT>
__device__ __forceinline__ void gemm_tile(const short* A, const short* W, int m0, int n0,
                                          short* Als, short* Bls, int tid, int mw, int nw,
                                          int l31, int lh, f32x16& acc) {
#pragma unroll
  for (int i = 0; i < 16; i++) acc[i] = 0.f;
  for (int kc = 0; kc < KTOT; kc += 96) {
    __syncthreads();
#pragma unroll
    for (int i = 0; i < 3; i++) {
      int seg = tid + i * 256;
      int r = seg / 12, s = seg - r * 12;
      *(s16x8*)(Als + r * 104 + s * 8) =
          *(const s16x8*)(A + (size_t)(m0 + r) * KTOT + kc + s * 8);
      *(s16x8*)(Bls + r * 104 + s * 8) =
          *(const s16x8*)(W + (size_t)(n0 + r) * KTOT + kc + s * 8);
    }
    __syncthreads();
#pragma unroll
    for (int ks = 0; ks < 6; ks++) {
      s16x8 af = *(const s16x8*)(Als + (mw + l31) * 104 + ks * 16 + lh * 8);
      s16x8 bf = *(const s16x8*)(Bls + (nw + l31) * 104 + ks * 16 + lh * 8);
      acc = __builtin_amdgcn_mfma_f32_32x32x16_bf16(af, bf, acc, 0, 0, 0);
    }
  }
}

__device__ __forceinline__ void scan1_body(int b, int ch, int d, int job,
                                           const __hip_bfloat16* xa, const float* bcd,
                                           const float* Aneg, const float* w_dt,
                                           const float* b_dt, float* Pst, float* Hst) {
  int l0 = ch * CHL;
  int lim = (CHL < L_ - l0) ? CHL : (L_ - l0);
  float Av[16];
#pragma unroll
  for (int q = 0; q < 4; q++) {
    float4 v = *(const float4*)(Aneg + d * 16 + q * 4);
    Av[q * 4] = v.x; Av[q * 4 + 1] = v.y; Av[q * 4 + 2] = v.z; Av[q * 4 + 3] = v.w;
  }
  float wdt = w_dt[d], bdt = b_dt[d];
  const __hip_bfloat16* xap = xa + ((size_t)b * L_ + l0) * DI_ + d;
  const float* bp = bcd + ((size_t)b * L_ + l0) * 64;
  float h[16], Pp[16];
#pragma unroll
  for (int n = 0; n < 16; n++) { h[n] = 0.f; Pp[n] = 1.f; }
  for (int j = 0; j < lim; j++) {
    float xv = __bfloat162float(xap[(size_t)j * DI_]);
    float dtraw = bp[j * 64 + 32];
    float Bn[16];
#pragma unroll
    for (int n = 0; n < 16; n++) Bn[n] = bp[j * 64 + n];
    float v = fmaf(dtraw, wdt, bdt);
    float dtv = (v > 20.f) ? v : __logf(1.f + __expf(v));
    float dtx = dtv * xv;
#pragma unroll
    for (int n = 0; n < 16; n++) {
      float dA = __expf(dtv * Av[n]);
      h[n] = fmaf(dA, h[n], dtx * Bn[n]);
      Pp[n] *= dA;
    }
  }
  size_t s = ((size_t)job * 384 + d) * 16;
#pragma unroll
  for (int q = 0; q < 4; q++) {
    *(float4*)(Pst + s + q * 4) = make_float4(Pp[q * 4], Pp[q * 4 + 1], Pp[q * 4 + 2], Pp[q * 4 + 3]);
    *(float4*)(Hst + s + q * 4) = make_float4(h[q * 4], h[q * 4 + 1], h[q * 4 + 2], h[q * 4 + 3]);
  }
}

__device__ __forceinline__ void scan2_body(int b, int ch, int d,
                                           const __hip_bfloat16* xa, const __hip_bfloat16* sz,
                                           const float* bcd, const float* Aneg,
                                           const float* D_ssm, const float* w_dt,
                                           const float* b_dt, const float* Pst,
                                           const float* Hst, __hip_bfloat16* y) {
  int l0 = ch * CHL;
  int lim = (CHL < L_ - l0) ? CHL : (L_ - l0);
  float Av[16];
#pragma unroll
  for (int q = 0; q < 4; q++) {
    float4 v = *(const float4*)(Aneg + d * 16 + q * 4);
    Av[q * 4] = v.x; Av[q * 4 + 1] = v.y; Av[q * 4 + 2] = v.z; Av[q * 4 + 3] = v.w;
  }
  float Dv = D_ssm[d];
  float wdt = w_dt[d], bdt = b_dt[d];
  float h[16];
#pragma unroll
  for (int n = 0; n < 16; n++) h[n] = 0.f;
  for (int c = 0; c < ch; c++) {
    size_t o = ((size_t)(b * NCH + c) * 384 + d) * 16;
#pragma unroll
    for (int q = 0; q < 4; q++) {
      float4 P = *(const float4*)(Pst + o + q * 4);
      float4 H = *(const float4*)(Hst + o + q * 4);
      h[q * 4]     = fmaf(P.x, h[q * 4],     H.x);
      h[q * 4 + 1] = fmaf(P.y, h[q * 4 + 1], H.y);
      h[q * 4 + 2] = fmaf(P.z, h[q * 4 + 2], H.z);
      h[q * 4 + 3] = fmaf(P.w, h[q * 4 + 3], H.w);
    }
  }
  const __hip_bfloat16* xap = xa + ((size_t)b * L_ + l0) * DI_ + d;
  const __hip_bfloat16* szp = sz + ((size_t)b * L_ + l0) * DI_ + d;
  const float* bp = bcd + ((size_t)b * L_ + l0) * 64;
  __hip_bfloat16* yp = y + ((size_t)b * L_ + l0) * DI_ + d;
  for (int j = 0; j < lim; j++) {
    float xv = __bfloat162float(xap[(size_t)j * DI_]);
    float szv = __bfloat162float(szp[(size_t)j * DI_]);
    float dtraw = bp[j * 64 + 32];
    float Bn[16], Cn[16];
#pragma unroll
    for (int n = 0; n < 16; n++) Bn[n] = bp[j * 64 + n];
#pragma unroll
    for (int n = 0; n < 16; n++) Cn[n] = bp[j * 64 + 16 + n];
    float v = fmaf(dtraw, wdt, bdt);
    float dtv = (v > 20.f) ? v : __logf(1.f + __expf(v));
    float dtx = dtv * xv;
    float acc = 0.f;
#pragma unroll
    for (int n = 0; n < 16; n++) {
      float dA = __expf(dtv * Av[n]);
      h[n] = fmaf(dA, h[n], dtx * Bn[n]);
      acc = fmaf(h[n], Cn[n], acc);
    }
    yp[(size_t)j * DI_] = __float2bfloat16(fmaf(xv, Dv, acc) * szv);
  }
}

// ---------------- the persistent mega-kernel ----------------
__global__ __launch_bounds__(256, 2) void k_mega(MP p) {
  __shared__ __align__(16) short Als[64 * 104];
  __shared__ __align__(16) short Bls[64 * 104];
  __shared__ float hred[8];
  __shared__ float hstats[2];
  __shared__ float hfeat[192];
  __shared__ float hh[96];
  int tid = threadIdx.x;
  int lane = tid & 63, wid = tid >> 6;
  int mw = (wid & 1) * 32, nw = (wid >> 1) * 32;
  int l31 = lane & 31, lh = lane >> 5;
  unsigned int* cnt = p.bar;
  unsigned int* gen = p.bar + 1;

  // ---- stage 0: patch GEMM (294 jobs), epilogue -> t with bias+pos ----
  for (int job = blockIdx.x; job < 294; job += GRID_) {
    int m0 = (job % 98) * 64, n0 = (job / 98) * 64;
    f32x16 acc;
    gemm_tile<768>(p.Abuf, p.pw, m0, n0, Als, Bls, tid, mw, nw, l31, lh, acc);
    int gn = n0 + nw + l31;
#pragma unroll
    for (int i = 0; i < 16; i++) {
      int rowt = mw + (i & 3) + 8 * (i >> 2) + 4 * lh;
      int gm = m0 + rowt;
      int b = gm / 196, pp = gm - b * 196;
      p.t[((size_t)b * 197 + 1 + pp) * 192 + gn] =
          acc[i] + p.patch_b[gn] + p.pos[(size_t)(1 + pp) * 192 + gn];
    }
  }
  gsync(cnt, gen);

  for (int layer = 0; layer < DEPTH_; layer++) {
    const float* g_ = p.ln_g + layer * D_;
    const float* bb_ = p.ln_b + layer * D_;
    const short* win_ = p.win + (size_t)layer * 147456;
    const float* cw_ = p.conv_w + layer * DI_ * DC_;
    const float* cb_ = p.conv_b + layer * DI_;
    const short* wx_ = p.wx + (size_t)layer * 24576;
    const float* An_ = p.Aneg + layer * 6144;
    const float* wdt_ = p.w_dt + layer * DI_;
    const float* bdt_ = p.b_dt + layer * DI_;
    const float* Ds_ = p.D_ssm + layer * DI_;
    const short* wo_ = p.wout + (size_t)layer * 73728;

    // ---- LN: 1576 jobs of 4 tokens ----
    for (int job = blockIdx.x; job < 1576; job += GRID_) {
      int tok = job * 4 + wid;
      int t64 = lane;
      const float* xr = p.t + (size_t)tok * D_;
      float x0 = xr[t64], x1 = xr[t64 + 64], x2 = xr[t64 + 128];
      float s = x0 + x1 + x2;
      float q = x0 * x0 + x1 * x1 + x2 * x2;
#pragma unroll
      for (int off = 1; off < 64; off <<= 1) {
        s += __shfl_xor(s, off, 64);
        q += __shfl_xor(q, off, 64);
      }
      float m = s * (1.f / 192.f);
      float r = rsqrtf(q * (1.f / 192.f) - m * m + 1e-5f);
      __hip_bfloat16* orow = p.xln + (size_t)tok * D_;
      orow[t64]       = __float2bfloat16((x0 - m) * r * g_[t64]       + bb_[t64]);
      orow[t64 + 64]  = __float2bfloat16((x1 - m) * r * g_[t64 + 64]  + bb_[t64 + 64]);
      orow[t64 + 128] = __float2bfloat16((x2 - m) * r * g_[t64 + 128] + bb_[t64 + 128]);
    }
    gsync(cnt, gen);

    // ---- Gin: xz = xln @ win^T, 1188 jobs ----
    for (int job = blockIdx.x; job < 1188; job += GRID_) {
      int m0 = (job / 12) * 64, n0 = (job % 12) * 64;
      f32x16 acc;
      gemm_tile<192>((const short*)p.xln, win_, m0, n0, Als, Bls, tid, mw, nw, l31, lh, acc);
      int gn = n0 + nw + l31;
#pragma unroll
      for (int i = 0; i < 16; i++) {
        int rowt = mw + (i & 3) + 8 * (i >> 2) + 4 * lh;
        int gm = m0 + rowt;
        if (gm < 6304) p.xz[(size_t)gm * 768 + gn] = __float2bfloat16(acc[i]);
      }
    }
    gsync(cnt, gen);

    // ---- conv + silu (elementwise) ----
    {
      const short* xzs = (const short*)p.xz;
      for (int idx = blockIdx.x * 256 + tid; idx < 6304 * 384; idx += GRID_ * 256) {
        int tok = idx / 384;
        int d = idx - tok * 384;
        int l = tok % 197;
        float4 c4 = *(const float4*)(cw_ + d * 4);
        float a = fmaf(c4.w, bf2f(xzs[(size_t)tok * 768 + d]), cb_[d]);
        if (l >= 1) a = fmaf(c4.z, bf2f(xzs[(size_t)(tok - 1) * 768 + d]), a);
        if (l >= 2) a = fmaf(c4.y, bf2f(xzs[(size_t)(tok - 2) * 768 + d]), a);
        if (l >= 3) a = fmaf(c4.x, bf2f(xzs[(size_t)(tok - 3) * 768 + d]), a);
        float xav = a * sigmoidf_(a);
        ((short*)p.xa)[(size_t)tok * 384 + d] = f2bf(xav);
        float z = bf2f(xzs[(size_t)tok * 768 + 384 + d]);
        ((short*)p.sz)[(size_t)tok * 384 + d] = f2bf(z * sigmoidf_(z));
      }
    }
    gsync(cnt, gen);

    // ---- bcd = xa @ wx^T, 99 jobs ----
    for (int job = blockIdx.x; job < 99; job += GRID_) {
      int m0 = job * 64;
      f32x16 acc;
      gemm_tile<384>((const short*)p.xa, wx_, m0, 0, Als, Bls, tid, mw, nw, l31, lh, acc);
      int gn = nw + l31;
#pragma unroll
      for (int i = 0; i < 16; i++) {
        int rowt = mw + (i & 3) + 8 * (i >> 2) + 4 * lh;
        int gm = m0 + rowt;
        if (gm < 6304) p.bcd[(size_t)gm * 64 + gn] = acc[i];
      }
    }
    gsync(cnt, gen);

    // ---- scan1: 512 jobs (b,ch), d strided by 256 ----
    for (int job = blockIdx.x; job < B_ * NCH; job += GRID_) {
      int b = job >> 4, ch = job & 15;
      for (int d = tid; d < 384; d += 256)
        scan1_body(b, ch, d, job, p.xa, p.bcd, An_, wdt_, bdt_, p.Pst, p.Hst);
    }
    gsync(cnt, gen);

    // ---- scan2: 512 jobs, inline lookback ----
    for (int job = blockIdx.x; job < B_ * NCH; job += GRID_) {
      int b = job >> 4, ch = job & 15;
      for (int d = tid; d < 384; d += 256)
        scan2_body(b, ch, d, p.xa, p.sz, p.bcd, An_, Ds_, wdt_, bdt_, p.Pst, p.Hst, p.y);
    }
    gsync(cnt, gen);

    // ---- Gout: t += y @ wout^T, 297 jobs ----
    for (int job = blockIdx.x; job < 297; job += GRID_) {
      int m0 = (job % 99) * 64, n0 = (job / 99) * 64;
      f32x16 acc;
      gemm_tile<384>((const short*)p.y, wo_, m0, n0, Als, Bls, tid, mw, nw, l31, lh, acc);
      int gn = n0 + nw + l31;
#pragma unroll
      for (int i = 0; i < 16; i++) {
        int rowt = mw + (i & 3) + 8 * (i >> 2) + 4 * lh;
        int gm = m0 + rowt;
        if (gm < 6304) p.t[(size_t)gm * 192 + gn] += acc[i];
      }
    }
    gsync(cnt, gen);
  }

  // ---- head: blocks 0..31 (256 threads; tid<192 active, barriers unconditional) ----
  if (blockIdx.x < 32) {
    int b = blockIdx.x;
    bool act = tid < 192;
    float x = act ? p.t[(size_t)b * L_ * D_ + tid] : 0.f;
    float s = x, q = x * x;
#pragma unroll
    for (int off = 1; off < 64; off <<= 1) {
      s += __shfl_xor(s, off, 64);
      q += __shfl_xor(q, off, 64);
    }
    if (lane == 0 && wid < 3) { hred[wid] = s; hred[4 + wid] = q; }
    __syncthreads();
    if (tid == 0) {
      float ss = hred[0] + hred[1] + hred[2];
      float qq = hred[4] + hred[5] + hred[6];
      float m = ss * (1.f / 192.f);
      hstats[0] = m;
      hstats[1] = rsqrtf(qq * (1.f / 192.f) - m * m + 1e-5f);
    }
    __syncthreads();
    if (act) hfeat[tid] = (x - hstats[0]) * hstats[1] * p.fn_g[tid] + p.fn_b[tid];
    __syncthreads();
    if (tid < 96) {
      float a = p.rb1[tid];
      const float* wr = p.rw1 + (size_t)tid * 192;
      for (int k = 0; k < 192; k++) a = fmaf(hfeat[k], wr[k], a);
      hh[tid] = 0.5f * a * (1.f + erff(a * 0.70710678118654752f));
    } else if (tid < 98) {
      int c = tid - 96;
      float a = p.cls_b[c];
      const float* wr = p.cls_w + (size_t)c * 192;
      for (int k = 0; k < 192; k++) a = fmaf(hfeat[k], wr[k], a);
      p.out[b * 2 + c] = a;
    }
    __syncthreads();
    if (tid == 0) {
      float a = p.rb2[0];
      for (int j = 0; j < 96; j++) a = fmaf(hh[j], p.rw2[j], a);
      p.out[64 + b] = a;
    }
  }
}

extern "C" void kernel_launch(void* const* d_in, const int* in_sizes, int n_in,
                              void* d_out, int out_size, void* d_ws, size_t ws_size,
                              hipStream_t stream) {
  const float* x       = (const float*)d_in[0];
  const float* patch_w = (const float*)d_in[1];
  const float* patch_b = (const float*)d_in[2];
  const float* cls_tok = (const float*)d_in[3];
  const float* pos     = (const float*)d_in[4];
  const float* ln_g    = (const float*)d_in[5];
  const float* ln_b    = (const float*)d_in[6];
  const float* w_in    = (const float*)d_in[7];
  const float* conv_w  = (const float*)d_in[8];
  const float* conv_b  = (const float*)d_in[9];
  const float* w_x     = (const float*)d_in[10];
  const float* w_dt    = (const float*)d_in[11];
  const float* b_dt    = (const float*)d_in[12];
  const float* A_log   = (const float*)d_in[13];
  const float* D_ssm   = (const float*)d_in[14];
  const float* w_out   = (const float*)d_in[15];
  const float* fn_g    = (const float*)d_in[16];
  const float* fn_b    = (const float*)d_in[17];
  const float* cls_w   = (const float*)d_in[18];
  const float* cls_b   = (const float*)d_in[19];
  const float* reg_w1  = (const float*)d_in[20];
  const float* reg_b1  = (const float*)d_in[21];
  const float* reg_w2  = (const float*)d_in[22];
  const float* reg_b2  = (const float*)d_in[23];
  float* out = (float*)d_out;

  float* ws = (float*)d_ws;
  // barrier state (zeroed every call via memset below)
  unsigned int* bar = (unsigned int*)ws;     // 2 uints, padded to 16 floats
  // fp32 region
  float* t_buf = ws + 16;                    // 1,210,368
  float* bcd   = t_buf + 1210368;            // 6336*64 = 405,504
  float* Pst   = bcd + 405504;               // 32*16*6144 = 3,145,728
  float* Hst   = Pst + 3145728;              // 3,145,728
  float* Aneg  = Hst + 3145728;              // 24,576
  // bf16 region
  __hip_bfloat16* xz_bf  = (__hip_bfloat16*)(Aneg + 24576);  // 6304*768 = 4,841,472
  __hip_bfloat16* Abuf   = xz_bf;            // alias: im2col output dead after patch gemm
  __hip_bfloat16* xa_bf  = xz_bf + 4841472;  // 6336*384 = 2,433,024
  __hip_bfloat16* sz_bf  = xa_bf + 2433024;  // 2,433,024
  __hip_bfloat16* xln_bf = sz_bf + 2433024;  // 6336*192 = 1,216,512
  __hip_bfloat16* y_bf   = xln_bf + 1216512; // 2,433,024
  __hip_bfloat16* pw_bf  = y_bf + 2433024;   // 147,456
  __hip_bfloat16* win_bf = pw_bf + 147456;   // 589,824
  __hip_bfloat16* wout_bf = win_bf + 589824; // 294,912
  __hip_bfloat16* wx_bf  = wout_bf + 294912; // 98,304

  hipMemsetAsync(bar, 0, 8, stream);
  k_prep_im2col<<<23352, 256, 0, stream>>>(x, Abuf, patch_w, w_in, w_out, w_x,
                                           cls_tok, pos, A_log, pw_bf, win_bf,
                                           wout_bf, wx_bf, t_buf, Aneg);
  MP p;
  p.Abuf = (const short*)Abuf; p.pw = (const short*)pw_bf;
  p.patch_b = patch_b; p.pos = pos;
  p.t = t_buf;
  p.ln_g = ln_g; p.ln_b = ln_b;
  p.win = (const short*)win_bf;
  p.xln = xln_bf; p.xz = xz_bf;
  p.conv_w = conv_w; p.conv_b = conv_b;
  p.xa = xa_bf; p.sz = sz_bf;
  p.wx = (const short*)wx_bf;
  p.bcd = bcd;
  p.Aneg = Aneg; p.w_dt = w_dt; p.b_dt = b_dt; p.D_ssm = D_ssm;
  p.Pst = Pst; p.Hst = Hst;
  p.y = y_bf;
  p.wout = (const short*)wout_bf;
  p.fn_g = fn_g; p.fn_b = fn_b; p.cls_w = cls_w; p.cls_b = cls_b;
  p.rw1 = reg_w1; p.rb1 = reg_b1; p.rw2 = reg_w2; p.rb2 = reg_b2;
  p.out = out;
  p.bar = bar;
  k_mega<<<GRID_, 256, 0, stream>>>(p);
}

// Round 13
// 556.377 us; speedup vs baseline: 6.5416x; 6.5416x over previous
//
#include <hip/hip_runtime.h>
#include <hip/hip_bf16.h>
#include <math.h>

// Problem constants
#define B_ 32
#define D_ 192
#define DEPTH_ 4
#define DI_ 384
#define DS_ 16
#define DC_ 4
#define P_ 16
#define IMG_ 224
#define N_ 196
#define L_ 197

// scan chunking
#define NCH 16
#define CHL 13   // 16*13 = 208 >= 197

typedef short s16x8 __attribute__((ext_vector_type(8)));
typedef float f32x16 __attribute__((ext_vector_type(16)));

__device__ __forceinline__ float sigmoidf_(float x) { return 1.f / (1.f + expf(-x)); }
__device__ __forceinline__ short f2bf(float f) {
  __hip_bfloat16 h = __float2bfloat16(f);
  return *(short*)&h;
}

// ---------------- merged im2col + prep ----------------
__global__ __launch_bounds__(256) void k_prep_im2col(
    const float* __restrict__ x, __hip_bfloat16* __restrict__ A,
    const float* __restrict__ patch_w, const float* __restrict__ w_in,
    const float* __restrict__ w_out, const float* __restrict__ w_x,
    const float* __restrict__ cls_tok, const float* __restrict__ pos,
    const float* __restrict__ A_log,
    __hip_bfloat16* __restrict__ pw, __hip_bfloat16* __restrict__ win,
    __hip_bfloat16* __restrict__ wout, __hip_bfloat16* __restrict__ wx,
    float* __restrict__ t, float* __restrict__ Aneg) {
  if (blockIdx.x < 18816) {
    int idx = blockIdx.x * 256 + threadIdx.x;  // 6272*768 exact
    int tok = idx / 768, f = idx - tok * 768;
    int b = tok / 196, p = tok - b * 196;
    int h = p / 14, w = p - h * 14;
    int c = f >> 8, i = (f >> 4) & 15, j = f & 15;
    float v = x[(((size_t)(b * 3 + c) * 224 + h * 16 + i) * 224 + w * 16 + j)];
    A[idx] = __float2bfloat16(v);
    return;
  }
  int idx = (blockIdx.x - 18816) * 256 + threadIdx.x;  // 1,161,216 exact
  if (idx < 147456) { pw[idx] = __float2bfloat16(patch_w[idx]); return; }
  idx -= 147456;
  if (idx < 589824) { win[idx] = __float2bfloat16(w_in[idx]); return; }
  idx -= 589824;
  if (idx < 294912) { wout[idx] = __float2bfloat16(w_out[idx]); return; }
  idx -= 294912;
  if (idx < 98304) {
    int li = idx / 24576;
    int r = (idx / 384) & 63;
    int c = idx % 384;
    wx[idx] = (r < 33) ? __float2bfloat16(w_x[(li * 33 + r) * 384 + c]) : __float2bfloat16(0.f);
    return;
  }
  idx -= 98304;
  if (idx < 6144) {
    int b = idx / 192, d = idx % 192;
    t[(size_t)b * L_ * D_ + d] = cls_tok[d] + pos[d];
    return;
  }
  idx -= 6144;
  Aneg[idx] = -expf(A_log[idx]);  // 24576
}

// ---------------- generic bf16 MFMA GEMM (modes 1,2,3) ----------------
// r7-verified shape: KC=96, STR=104 (26.6 KB LDS). Do NOT grow LDS here.
// MODE 1: C fp32 (stride 192) += acc                 (t += y @ w_out^T)
// MODE 2: patch epilogue into t (fp32)
// MODE 3: C fp32 (stride 64) = acc                   (bcd = xa @ w_x_pad^T)
template <int KTOT, int MODE>
__global__ __launch_bounds__(256) void k_gemm_mfma(const short* __restrict__ A,
                                                   const short* __restrict__ Wb,
                                                   float* __restrict__ C,
                                                   const float* __restrict__ bias,
                                                   const float* __restrict__ pos,
                                                   int M) {
  constexpr int KC = 96;
  constexpr int STR = 104;
  __shared__ __align__(16) short Als[64 * STR];
  __shared__ __align__(16) short Bls[64 * STR];
  int m0 = blockIdx.x * 64, n0 = blockIdx.y * 64;
  int tid = threadIdx.x;
  int lane = tid & 63, wid = tid >> 6;
  int mw = (wid & 1) * 32, nw = (wid >> 1) * 32;
  int l31 = lane & 31, lh = lane >> 5;
  f32x16 acc;
#pragma unroll
  for (int i = 0; i < 16; i++) acc[i] = 0.f;
  for (int kc = 0; kc < KTOT; kc += KC) {
    __syncthreads();
#pragma unroll
    for (int i = 0; i < 3; i++) {
      int seg = tid + i * 256;
      int r = seg / 12, s = seg - r * 12;
      *(s16x8*)(Als + r * STR + s * 8) =
          *(const s16x8*)(A + (size_t)(m0 + r) * KTOT + kc + s * 8);
      *(s16x8*)(Bls + r * STR + s * 8) =
          *(const s16x8*)(Wb + (size_t)(n0 + r) * KTOT + kc + s * 8);
    }
    __syncthreads();
#pragma unroll
    for (int ks = 0; ks < KC / 16; ks++) {
      s16x8 af = *(const s16x8*)(Als + (mw + l31) * STR + ks * 16 + lh * 8);
      s16x8 bf = *(const s16x8*)(Bls + (nw + l31) * STR + ks * 16 + lh * 8);
      acc = __builtin_amdgcn_mfma_f32_32x32x16_bf16(af, bf, acc, 0, 0, 0);
    }
  }
  // epilogue: C/D layout col=lane&31, row=(reg&3)+8*(reg>>2)+4*(lane>>5)
  int gn = n0 + nw + l31;
#pragma unroll
  for (int i = 0; i < 16; i++) {
    int rowt = mw + (i & 3) + 8 * (i >> 2) + 4 * lh;
    int gm = m0 + rowt;
    float v = acc[i];
    if (MODE == 1) {
      if (gm < M) C[(size_t)gm * 192 + gn] += v;
    } else if (MODE == 3) {
      if (gm < M) C[(size_t)gm * 64 + gn] = v;
    } else {
      int b = gm / 196, p = gm - b * 196;
      C[((size_t)b * 197 + 1 + p) * 192 + gn] =
          v + bias[gn] + pos[(size_t)(1 + p) * 192 + gn];
    }
  }
}

// ---------------- fused LN + Gin: xz = LN(t) @ w_in^T ----------------
// Grid (99,12), 256 thr. LDS stays 26.6 KB (occupancy preserved — r9's 51 KB
// version halved occupancy and regressed; don't grow LDS). LN stats computed
// once per block into 512 B LDS; A-tile staging reads t (fp32, L2-hot) and
// applies LN during the bf16 pack.
__global__ __launch_bounds__(256) void k_gemm_in_ln(const float* __restrict__ t,
                                                    const float* __restrict__ g,
                                                    const float* __restrict__ bb,
                                                    const short* __restrict__ Wb,
                                                    __hip_bfloat16* __restrict__ xz) {
  constexpr int STR = 104;
  __shared__ __align__(16) short Als[64 * STR];
  __shared__ __align__(16) short Bls[64 * STR];
  __shared__ float lnm[64];
  __shared__ float lnr[64];
  int m0 = blockIdx.x * 64, n0 = blockIdx.y * 64;
  int tid = threadIdx.x;
  // LN stats: 4 threads per row, 48 cols each
  {
    int r = tid >> 2, part = tid & 3;
    int gm = m0 + r;
    int gmc = (gm < 6304) ? gm : 6303;
    const float* trow = t + (size_t)gmc * 192 + part * 48;
    float s = 0.f, q = 0.f;
#pragma unroll
    for (int i = 0; i < 12; i++) {
      float4 v = *(const float4*)(trow + i * 4);
      s += v.x + v.y + v.z + v.w;
      q += v.x * v.x + v.y * v.y + v.z * v.z + v.w * v.w;
    }
    s += __shfl_xor(s, 1, 4); s += __shfl_xor(s, 2, 4);
    q += __shfl_xor(q, 1, 4); q += __shfl_xor(q, 2, 4);
    if (part == 0) {
      float m = s * (1.f / 192.f);
      lnm[r] = m;
      lnr[r] = rsqrtf(q * (1.f / 192.f) - m * m + 1e-5f);
    }
  }
  int lane = tid & 63, wid = tid >> 6;
  int mw = (wid & 1) * 32, nw = (wid >> 1) * 32;
  int l31 = lane & 31, lh = lane >> 5;
  f32x16 acc;
#pragma unroll
  for (int i = 0; i < 16; i++) acc[i] = 0.f;
  for (int kc = 0; kc < 192; kc += 96) {
    __syncthreads();
#pragma unroll
    for (int i = 0; i < 3; i++) {
      int seg = tid + i * 256;
      int r = seg / 12, s = seg - r * 12;
      int gm = m0 + r;
      int gmc = (gm < 6304) ? gm : 6303;
      int k0 = kc + s * 8;
      float4 v0 = *(const float4*)(t + (size_t)gmc * 192 + k0);
      float4 v1 = *(const float4*)(t + (size_t)gmc * 192 + k0 + 4);
      float4 g0 = *(const float4*)(g + k0);
      float4 g1 = *(const float4*)(g + k0 + 4);
      float4 b0 = *(const float4*)(bb + k0);
      float4 b1 = *(const float4*)(bb + k0 + 4);
      float m = lnm[r], rv = lnr[r];
      s16x8 o;
      o[0] = f2bf(fmaf((v0.x - m) * rv, g0.x, b0.x));
      o[1] = f2bf(fmaf((v0.y - m) * rv, g0.y, b0.y));
      o[2] = f2bf(fmaf((v0.z - m) * rv, g0.z, b0.z));
      o[3] = f2bf(fmaf((v0.w - m) * rv, g0.w, b0.w));
      o[4] = f2bf(fmaf((v1.x - m) * rv, g1.x, b1.x));
      o[5] = f2bf(fmaf((v1.y - m) * rv, g1.y, b1.y));
      o[6] = f2bf(fmaf((v1.z - m) * rv, g1.z, b1.z));
      o[7] = f2bf(fmaf((v1.w - m) * rv, g1.w, b1.w));
      *(s16x8*)(Als + r * STR + s * 8) = o;
      *(s16x8*)(Bls + r * STR + s * 8) =
          *(const s16x8*)(Wb + (size_t)(n0 + r) * 192 + kc + s * 8);
    }
    __syncthreads();
#pragma unroll
    for (int ks = 0; ks < 6; ks++) {
      s16x8 af = *(const s16x8*)(Als + (mw + l31) * STR + ks * 16 + lh * 8);
      s16x8 bf = *(const s16x8*)(Bls + (nw + l31) * STR + ks * 16 + lh * 8);
      acc = __builtin_amdgcn_mfma_f32_32x32x16_bf16(af, bf, acc, 0, 0, 0);
    }
  }
  int gn = n0 + nw + l31;
#pragma unroll
  for (int i = 0; i < 16; i++) {
    int rowt = mw + (i & 3) + 8 * (i >> 2) + 4 * lh;
    int gm = m0 + rowt;
    if (gm < 6304) xz[(size_t)gm * 768 + gn] = __float2bfloat16(acc[i]);
  }
}

// ---------------- causal depthwise conv + silu: 8 tokens/block, LDS window (r7) ----------------
__global__ __launch_bounds__(384) void k_conv(const __hip_bfloat16* __restrict__ xz,
                                              const float* __restrict__ cw_,
                                              const float* __restrict__ cb,
                                              __hip_bfloat16* __restrict__ xa_bf,
                                              __hip_bfloat16* __restrict__ sz_bf) {
  __shared__ float xs[11][384];
  int r0 = blockIdx.x * 8;  // 788 blocks * 8 = 6304
  int d = threadIdx.x;
#pragma unroll
  for (int row = 0; row < 11; row++) {
    int gr = r0 - 3 + row;
    if (gr >= 0) xs[row][d] = __bfloat162float(xz[(size_t)gr * 768 + d]);
  }
  __syncthreads();
  float4 cw = *(const float4*)(cw_ + d * 4);
  float cbv = cb[d];
#pragma unroll
  for (int tk = 0; tk < 8; tk++) {
    int tok = r0 + tk;
    int l = tok % L_;
    float acc = fmaf(cw.w, xs[tk + 3][d], cbv);
    if (l >= 1) acc = fmaf(cw.z, xs[tk + 2][d], acc);
    if (l >= 2) acc = fmaf(cw.y, xs[tk + 1][d], acc);
    if (l >= 3) acc = fmaf(cw.x, xs[tk][d], acc);
    float xav = acc * sigmoidf_(acc);
    xa_bf[(size_t)tok * DI_ + d] = __float2bfloat16(xav);
    float z = __bfloat162float(xz[(size_t)tok * 768 + 384 + d]);
    sz_bf[(size_t)tok * DI_ + d] = __float2bfloat16(z * sigmoidf_(z));
  }
}

// ---------------- scan phase 1: chunk-local scan, store P (prod dA) and H_local ----------------
__global__ __launch_bounds__(384) void k_scan1(const __hip_bfloat16* __restrict__ xa,
                                               const float* __restrict__ bcd,
                                               const float* __restrict__ Aneg,
                                               const float* __restrict__ w_dt,
                                               const float* __restrict__ b_dt,
                                               float* __restrict__ Pst,
                                               float* __restrict__ Hst) {
  int b = blockIdx.x >> 4, ch = blockIdx.x & 15;
  int d = threadIdx.x;
  int l0 = ch * CHL;
  int lim = min(CHL, L_ - l0);
  float Av[16];
#pragma unroll
  for (int q = 0; q < 4; q++) {
    float4 v = *(const float4*)(Aneg + d * 16 + q * 4);
    Av[q * 4] = v.x; Av[q * 4 + 1] = v.y; Av[q * 4 + 2] = v.z; Av[q * 4 + 3] = v.w;
  }
  float wdt = w_dt[d], bdt = b_dt[d];
  const __hip_bfloat16* xap = xa + ((size_t)b * L_ + l0) * DI_ + d;
  const float* bp = bcd + ((size_t)b * L_ + l0) * 64;
  float h[16], Pp[16];
#pragma unroll
  for (int n = 0; n < 16; n++) { h[n] = 0.f; Pp[n] = 1.f; }
  for (int j = 0; j < lim; j++) {
    float xv = __bfloat162float(xap[(size_t)j * DI_]);
    float dtraw = bp[j * 64 + 32];
    float Bn[16];
#pragma unroll
    for (int n = 0; n < 16; n++) Bn[n] = bp[j * 64 + n];
    float v = fmaf(dtraw, wdt, bdt);
    float dtv = (v > 20.f) ? v : __logf(1.f + __expf(v));
    float dtx = dtv * xv;
#pragma unroll
    for (int n = 0; n < 16; n++) {
      float dA = __expf(dtv * Av[n]);
      h[n] = fmaf(dA, h[n], dtx * Bn[n]);
      Pp[n] *= dA;
    }
  }
  size_t s = ((size_t)blockIdx.x * 384 + d) * 16;
#pragma unroll
  for (int q = 0; q < 4; q++) {
    *(float4*)(Pst + s + q * 4) = make_float4(Pp[q * 4], Pp[q * 4 + 1], Pp[q * 4 + 2], Pp[q * 4 + 3]);
    *(float4*)(Hst + s + q * 4) = make_float4(h[q * 4], h[q * 4 + 1], h[q * 4 + 2], h[q * 4 + 3]);
  }
}

// ---------------- scan phase 2: inline lookback + rescan + C-dot + D + silu(z) ----------------
__global__ __launch_bounds__(384) void k_scan2(const __hip_bfloat16* __restrict__ xa,
                                               const __hip_bfloat16* __restrict__ sz,
                                               const float* __restrict__ bcd,
                                               const float* __restrict__ Aneg,
                                               const float* __restrict__ D_ssm,
                                               const float* __restrict__ w_dt,
                                               const float* __restrict__ b_dt,
                                               const float* __restrict__ Pst,
                                               const float* __restrict__ Hst,
                                               __hip_bfloat16* __restrict__ y) {
  int b = blockIdx.x >> 4, ch = blockIdx.x & 15;
  int d = threadIdx.x;
  int l0 = ch * CHL;
  int lim = min(CHL, L_ - l0);
  float Av[16];
#pragma unroll
  for (int q = 0; q < 4; q++) {
    float4 v = *(const float4*)(Aneg + d * 16 + q * 4);
    Av[q * 4] = v.x; Av[q * 4 + 1] = v.y; Av[q * 4 + 2] = v.z; Av[q * 4 + 3] = v.w;
  }
  float Dv = D_ssm[d];
  float wdt = w_dt[d], bdt = b_dt[d];
  // lookback: h = combine of chunks 0..ch-1 (algebra verified r8/r10)
  float h[16];
#pragma unroll
  for (int n = 0; n < 16; n++) h[n] = 0.f;
  for (int c = 0; c < ch; c++) {
    size_t o = ((size_t)(b * NCH + c) * 384 + d) * 16;
#pragma unroll
    for (int q = 0; q < 4; q++) {
      float4 P = *(const float4*)(Pst + o + q * 4);
      float4 H = *(const float4*)(Hst + o + q * 4);
      h[q * 4]     = fmaf(P.x, h[q * 4],     H.x);
      h[q * 4 + 1] = fmaf(P.y, h[q * 4 + 1], H.y);
      h[q * 4 + 2] = fmaf(P.z, h[q * 4 + 2], H.z);
      h[q * 4 + 3] = fmaf(P.w, h[q * 4 + 3], H.w);
    }
  }
  const __hip_bfloat16* xap = xa + ((size_t)b * L_ + l0) * DI_ + d;
  const __hip_bfloat16* szp = sz + ((size_t)b * L_ + l0) * DI_ + d;
  const float* bp = bcd + ((size_t)b * L_ + l0) * 64;
  __hip_bfloat16* yp = y + ((size_t)b * L_ + l0) * DI_ + d;
  for (int j = 0; j < lim; j++) {
    float xv = __bfloat162float(xap[(size_t)j * DI_]);
    float szv = __bfloat162float(szp[(size_t)j * DI_]);
    float dtraw = bp[j * 64 + 32];
    float Bn[16], Cn[16];
#pragma unroll
    for (int n = 0; n < 16; n++) Bn[n] = bp[j * 64 + n];
#pragma unroll
    for (int n = 0; n < 16; n++) Cn[n] = bp[j * 64 + 16 + n];
    float v = fmaf(dtraw, wdt, bdt);
    float dtv = (v > 20.f) ? v : __logf(1.f + __expf(v));
    float dtx = dtv * xv;
    float acc = 0.f;
#pragma unroll
    for (int n = 0; n < 16; n++) {
      float dA = __expf(dtv * Av[n]);
      h[n] = fmaf(dA, h[n], dtx * Bn[n]);
      acc = fmaf(h[n], Cn[n], acc);
    }
    yp[(size_t)j * DI_] = __float2bfloat16(fmaf(xv, Dv, acc) * szv);
  }
}

// ---------------- final LN(token 0) + cls head + reg head ----------------
__global__ __launch_bounds__(192) void k_head(const float* __restrict__ t,
                                              const float* __restrict__ fn_g,
                                              const float* __restrict__ fn_b,
                                              const float* __restrict__ cls_w,
                                              const float* __restrict__ cls_b,
                                              const float* __restrict__ rw1,
                                              const float* __restrict__ rb1,
                                              const float* __restrict__ rw2,
                                              const float* __restrict__ rb2,
                                              float* __restrict__ out) {
  __shared__ float red[8];
  __shared__ float stats[2];
  __shared__ float feat_s[192];
  __shared__ float h_s[96];
  int b = blockIdx.x, tid = threadIdx.x;
  float x = t[(size_t)b * L_ * D_ + tid];
  float s = x, q = x * x;
#pragma unroll
  for (int off = 1; off < 64; off <<= 1) {
    s += __shfl_xor(s, off, 64);
    q += __shfl_xor(q, off, 64);
  }
  int w = tid >> 6;
  if ((tid & 63) == 0) { red[w] = s; red[4 + w] = q; }
  __syncthreads();
  if (tid == 0) {
    float ss = red[0] + red[1] + red[2];
    float qq = red[4] + red[5] + red[6];
    float m = ss * (1.f / 192.f);
    stats[0] = m;
    stats[1] = rsqrtf(qq * (1.f / 192.f) - m * m + 1e-5f);
  }
  __syncthreads();
  float fv = (x - stats[0]) * stats[1] * fn_g[tid] + fn_b[tid];
  feat_s[tid] = fv;
  __syncthreads();
  if (tid < 96) {
    float a = rb1[tid];
    const float* wr = rw1 + (size_t)tid * 192;
    for (int k = 0; k < 192; k++) a = fmaf(feat_s[k], wr[k], a);
    h_s[tid] = 0.5f * a * (1.f + erff(a * 0.70710678118654752f));
  } else if (tid < 98) {
    int c = tid - 96;
    float a = cls_b[c];
    const float* wr = cls_w + (size_t)c * 192;
    for (int k = 0; k < 192; k++) a = fmaf(feat_s[k], wr[k], a);
    out[b * 2 + c] = a;
  }
  __syncthreads();
  if (tid == 0) {
    float a = rb2[0];
    for (int j = 0; j < 96; j++) a = fmaf(h_s[j], rw2[j], a);
    out[64 + b] = a;
  }
}

extern "C" void kernel_launch(void* const* d_in, const int* in_sizes, int n_in,
                              void* d_out, int out_size, void* d_ws, size_t ws_size,
                              hipStream_t stream) {
  const float* x       = (const float*)d_in[0];
  const float* patch_w = (const float*)d_in[1];
  const float* patch_b = (const float*)d_in[2];
  const float* cls_tok = (const float*)d_in[3];
  const float* pos     = (const float*)d_in[4];
  const float* ln_g    = (const float*)d_in[5];
  const float* ln_b    = (const float*)d_in[6];
  const float* w_in    = (const float*)d_in[7];
  const float* conv_w  = (const float*)d_in[8];
  const float* conv_b  = (const float*)d_in[9];
  const float* w_x     = (const float*)d_in[10];
  const float* w_dt    = (const float*)d_in[11];
  const float* b_dt    = (const float*)d_in[12];
  const float* A_log   = (const float*)d_in[13];
  const float* D_ssm   = (const float*)d_in[14];
  const float* w_out   = (const float*)d_in[15];
  const float* fn_g    = (const float*)d_in[16];
  const float* fn_b    = (const float*)d_in[17];
  const float* cls_w   = (const float*)d_in[18];
  const float* cls_b   = (const float*)d_in[19];
  const float* reg_w1  = (const float*)d_in[20];
  const float* reg_b1  = (const float*)d_in[21];
  const float* reg_w2  = (const float*)d_in[22];
  const float* reg_b2  = (const float*)d_in[23];
  float* out = (float*)d_out;

  float* ws = (float*)d_ws;
  // fp32 region
  float* t_buf = ws;                         // 1,210,368
  float* bcd   = t_buf + 1210368;            // 6336*64 = 405,504
  float* Pst   = bcd + 405504;               // 32*16*6144 = 3,145,728
  float* Hst   = Pst + 3145728;              // 3,145,728
  float* Aneg  = Hst + 3145728;              // 24,576
  // bf16 region
  __hip_bfloat16* xz_bf  = (__hip_bfloat16*)(Aneg + 24576);  // 6304*768 = 4,841,472
  __hip_bfloat16* Abuf   = xz_bf;            // alias: im2col output dead after patch gemm
  __hip_bfloat16* xa_bf  = xz_bf + 4841472;  // 6336*384 = 2,433,024
  __hip_bfloat16* sz_bf  = xa_bf + 2433024;  // 2,433,024
  __hip_bfloat16* y_bf   = sz_bf + 2433024;  // 2,433,024
  __hip_bfloat16* pw_bf  = y_bf + 2433024;   // 147,456
  __hip_bfloat16* win_bf = pw_bf + 147456;   // 589,824
  __hip_bfloat16* wout_bf = win_bf + 589824; // 294,912
  __hip_bfloat16* wx_bf  = wout_bf + 294912; // 98,304

  k_prep_im2col<<<23352, 256, 0, stream>>>(x, Abuf, patch_w, w_in, w_out, w_x,
                                           cls_tok, pos, A_log, pw_bf, win_bf,
                                           wout_bf, wx_bf, t_buf, Aneg);
  k_gemm_mfma<768, 2><<<dim3(98, 3), 256, 0, stream>>>(
      (const short*)Abuf, (const short*)pw_bf, t_buf, patch_b, pos, 6272);

  for (int i = 0; i < DEPTH_; i++) {
    k_gemm_in_ln<<<dim3(99, 12), 256, 0, stream>>>(
        t_buf, ln_g + i * D_, ln_b + i * D_,
        (const short*)(win_bf + (size_t)i * 147456), xz_bf);
    k_conv<<<788, 384, 0, stream>>>(xz_bf, conv_w + i * DI_ * DC_, conv_b + i * DI_,
                                    xa_bf, sz_bf);
    k_gemm_mfma<384, 3><<<dim3(99, 1), 256, 0, stream>>>(
        (const short*)xa_bf, (const short*)(wx_bf + (size_t)i * 24576), bcd,
        nullptr, nullptr, 6304);
    k_scan1<<<B_ * NCH, 384, 0, stream>>>(xa_bf, bcd, Aneg + i * 6144,
                                          w_dt + i * DI_, b_dt + i * DI_, Pst, Hst);
    k_scan2<<<B_ * NCH, 384, 0, stream>>>(xa_bf, sz_bf, bcd, Aneg + i * 6144,
                                          D_ssm + i * DI_, w_dt + i * DI_, b_dt + i * DI_,
                                          Pst, Hst, y_bf);
    k_gemm_mfma<384, 1><<<dim3(99, 3), 256, 0, stream>>>(
        (const short*)y_bf, (const short*)(wout_bf + (size_t)i * 73728), t_buf,
        nullptr, nullptr, 6304);
  }
  k_head<<<32, 192, 0, stream>>>(t_buf, fn_g, fn_b, cls_w, cls_b, reg_w1, reg_b1,
                                 reg_w2, reg_b2, out);
}